// Round 11
// baseline (624.748 us; speedup 1.0000x reference)
//
#include <hip/hip_runtime.h>
#include <hip/hip_bf16.h>
#include <math.h>

#define D    64
#define F3   192
#define FS   128          // stored feats channels: [sum(64) | max(64)]
#define NPB  128          // nodes per bucket
#define SBITS 17          // src id fits in 17 bits (N=100000 < 131072)
#define NBLK 256          // edge blocks for binning passes
#define SCAN_CHUNK 2048   // 256 threads * 8 elements (== 1<<11)
#define MAXNB 800         // >= NB = ceil(N/NPB) = 782

using bf16x8 = __attribute__((ext_vector_type(8))) short;
using f32x4  = __attribute__((ext_vector_type(4))) float;

__device__ __forceinline__ ushort f2bf(float f) {
    __hip_bfloat16 h = __float2bfloat16(f);
    return *reinterpret_cast<ushort*>(&h);
}
__device__ __forceinline__ float bf2f(ushort u) {
    unsigned v = ((unsigned)u) << 16;
    return __uint_as_float(v);
}

// ---------------- A1 + pre-cast: hist | xcast | wcast by block range -------
__global__ __launch_bounds__(256) void k_cast_hist(
    const float* __restrict__ x, ushort* __restrict__ xb, int n4,
    const float* __restrict__ W, ushort* __restrict__ Wb, int nW,
    const int* __restrict__ dstv, unsigned* __restrict__ bcntT,
    int E, int EPB, int NB, int castBlocks)
{
    int bid = blockIdx.x;
    if (bid < NBLK) {
        __shared__ unsigned h[MAXNB];
        for (int i = threadIdx.x; i < NB; i += 256) h[i] = 0;
        __syncthreads();
        int lo = bid * EPB, hi = min(E, lo + EPB);
        for (int e = lo + threadIdx.x; e < hi; e += 256)
            atomicAdd(&h[((unsigned)dstv[e]) / NPB], 1u);
        __syncthreads();
        for (int i = threadIdx.x; i < NB; i += 256)
            bcntT[(size_t)i * NBLK + bid] = h[i];
    } else if (bid < NBLK + castBlocks) {
        int i = (bid - NBLK) * 256 + threadIdx.x;
        if (i < n4) {
            float4 v = *reinterpret_cast<const float4*>(x + (size_t)i * 4);
            ushort4 u = { f2bf(v.x), f2bf(v.y), f2bf(v.z), f2bf(v.w) };
            *reinterpret_cast<ushort4*>(xb + (size_t)i * 4) = u;
        }
    } else {
        for (int i = threadIdx.x; i < nW; i += 256) Wb[i] = f2bf(W[i]);
    }
}

// ---------------- A2: chunked exclusive scan of [bucket][block] counts ------
__global__ __launch_bounds__(256) void k_chunk_scan(
    const unsigned* __restrict__ cnt, unsigned* __restrict__ offs,
    unsigned* __restrict__ partials, int N)
{
    __shared__ unsigned ts[256];
    int t = threadIdx.x;
    int ebase = blockIdx.x * SCAN_CHUNK + t * 8;
    unsigned v[8];
    unsigned s = 0;
    #pragma unroll
    for (int j = 0; j < 8; ++j) {
        unsigned c = (ebase + j < N) ? cnt[ebase + j] : 0u;
        v[j] = s; s += c;
    }
    ts[t] = s;
    __syncthreads();
    #pragma unroll
    for (int off = 1; off < 256; off <<= 1) {
        unsigned add = (t >= off) ? ts[t - off] : 0u;
        __syncthreads();
        ts[t] += add;
        __syncthreads();
    }
    unsigned tb = (t > 0) ? ts[t - 1] : 0u;
    #pragma unroll
    for (int j = 0; j < 8; ++j)
        if (ebase + j < N) offs[ebase + j] = tb + v[j];
    if (t == 255) partials[blockIdx.x] = ts[255];
}

// A2b: in-place exclusive scan of chunk totals (1 block; removes per-block
// serial scans downstream).
__global__ void k_scan_partials(unsigned* partials, int n)
{
    if (blockIdx.x == 0 && threadIdx.x == 0) {
        unsigned s = 0;
        for (int i = 0; i < n; ++i) { unsigned c = partials[i]; partials[i] = s; s += c; }
    }
}

// ---------------- A3: scatter edges into bucket-grouped storage -------------
__global__ __launch_bounds__(256) void k_bin_scatter(
    const int* __restrict__ srcv, const int* __restrict__ dstv,
    const unsigned* __restrict__ bbaseT, const unsigned* __restrict__ partials,
    unsigned* __restrict__ binned, int E, int EPB, int NB)
{
    __shared__ unsigned cur[MAXNB];
    int t = threadIdx.x;
    for (int i = t; i < NB; i += 256) {
        unsigned idx = (unsigned)i * NBLK + blockIdx.x;
        cur[i] = bbaseT[idx] + partials[idx >> 11];
    }
    __syncthreads();
    int lo = blockIdx.x * EPB, hi = min(E, lo + EPB);
    for (int e = lo + t; e < hi; e += 256) {
        unsigned d = (unsigned)dstv[e];
        unsigned s = (unsigned)srcv[e];
        unsigned p = atomicAdd(&cur[d / NPB], 1u);
        binned[p] = ((d & (NPB - 1u)) << SBITS) | s;
    }
}

// ---------------- Phase B: bucket aggregation (LDS atomics) ----------------
// Block = 512 thr (8 waves) per 128-node bucket. LDS: sum f32 + max u32
// [128][64] (64.5 KB -> 2 blocks/CU). Each wave takes 8 edges/iter: decode
// packed (local<<17|src), 64-lane 128B row read (8 rows in flight), then
// ds_add_f32 (2-way bank, free) + ds_max_u32 on bias-encoded float
// (x+16 > 0 -> IEEE bits monotone as uint). No per-node serialization,
// no cross-lane reduction, no csr/ssrc pass.
__global__ __launch_bounds__(512) void k_bucket_agg(
    const unsigned* __restrict__ binned,
    const unsigned* __restrict__ bbaseT,
    const unsigned* __restrict__ partials,
    const ushort*   __restrict__ xb,      // [N][64] bf16
    unsigned* __restrict__ cnt,
    ushort*   __restrict__ feats,         // [N][128] bf16
    int E, int NB, int N)
{
    __shared__ float    sumf[NPB * 64];
    __shared__ unsigned maxe[NPB * 64];
    __shared__ unsigned cntl[NPB];

    int k = blockIdx.x;
    int t = threadIdx.x;

    for (int i = t; i < NPB * 64; i += 512) { sumf[i] = 0.0f; maxe[i] = 0u; }
    if (t < NPB) cntl[t] = 0u;

    unsigned i0 = (unsigned)k * NBLK;
    unsigned bstart = bbaseT[i0] + partials[i0 >> 11];
    unsigned bend;
    if (k + 1 < NB) {
        unsigned i1 = i0 + NBLK;
        bend = bbaseT[i1] + partials[i1 >> 11];
    } else bend = (unsigned)E;
    __syncthreads();

    unsigned lane = t & 63;
    unsigned w    = t >> 6;            // 8 waves

    for (unsigned base = bstart + (w << 3); base < bend; base += 64) {
        unsigned rem = bend - base;
        if (rem >= 8) {
            unsigned uu[8];
            #pragma unroll
            for (int j = 0; j < 8; ++j) uu[j] = binned[base + j];
            ushort bb[8];
            #pragma unroll
            for (int j = 0; j < 8; ++j)
                bb[j] = xb[((size_t)(uu[j] & 0x1FFFFu) << 6) | lane];
            #pragma unroll
            for (int j = 0; j < 8; ++j) {
                unsigned l = uu[j] >> SBITS;
                float f = bf2f(bb[j]);
                atomicAdd(&sumf[(l << 6) | lane], f);
                atomicMax(&maxe[(l << 6) | lane], __float_as_uint(f + 16.0f));
            }
            if (lane == 0) {
                #pragma unroll
                for (int j = 0; j < 8; ++j) atomicAdd(&cntl[uu[j] >> SBITS], 1u);
            }
        } else {
            for (unsigned j = 0; j < rem; ++j) {
                unsigned u = binned[base + j];
                unsigned l = u >> SBITS;
                float f = bf2f(xb[((size_t)(u & 0x1FFFFu) << 6) | lane]);
                atomicAdd(&sumf[(l << 6) | lane], f);
                atomicMax(&maxe[(l << 6) | lane], __float_as_uint(f + 16.0f));
                if (lane == 0) atomicAdd(&cntl[l], 1u);
            }
        }
    }
    __syncthreads();

    // epilogue: lane = channel (2-way LDS banks, free); 8 groups x 16 nodes.
    unsigned c  = t & 63;
    int      ng = t >> 6;
    for (int q = 0; q < 16; ++q) {
        int nd = ng * 16 + q;
        int gn = k * NPB + nd;
        if (gn >= N) break;
        unsigned dgn = cntl[nd];
        float sv = sumf[(nd << 6) | c];
        float mv = dgn ? __uint_as_float(maxe[(nd << 6) | c]) - 16.0f : 0.0f;
        feats[(size_t)gn * FS + c]      = f2bf(sv);
        feats[(size_t)gn * FS + 64 + c] = f2bf(mv);
    }
    if (t < NPB) {
        int gn = k * NPB + t;
        if (gn < N) cnt[gn] = cntl[t];
    }
}

// ---------------- Phase C: MFMA MLP ----------------
__global__ __launch_bounds__(256) void k_mlp2(
    const ushort*   __restrict__ feats,   // [N][128] bf16
    const unsigned* __restrict__ cnt,
    const ushort*   __restrict__ Wb,      // [64][192] bf16
    const float*    __restrict__ bias,    // [64]
    float*          __restrict__ out,     // [N][64]
    int N)
{
    int tid  = threadIdx.x;
    int lane = tid & 63;
    int wv   = tid >> 6;
    int l16  = lane & 15;
    int kb   = (lane >> 4) << 3;

    int col = (wv << 4) + l16;
    const ushort* wp = Wb + (size_t)col * F3 + kb;
    bf16x8 bS0 = *reinterpret_cast<const bf16x8*>(wp);
    bf16x8 bS1 = *reinterpret_cast<const bf16x8*>(wp + 32);
    bf16x8 bM0 = *reinterpret_cast<const bf16x8*>(wp + 64);
    bf16x8 bM1 = *reinterpret_cast<const bf16x8*>(wp + 96);
    bf16x8 bX0 = *reinterpret_cast<const bf16x8*>(wp + 128);
    bf16x8 bX1 = *reinterpret_cast<const bf16x8*>(wp + 160);
    float bo = bias[col];

    int n0 = blockIdx.x << 4;            // N divisible by 16

    unsigned dgr = cnt[n0 + l16];
    float inv = dgr ? 1.0f / (float)dgr : 0.0f;

    const ushort* arow = feats + (size_t)(n0 + l16) * FS + kb;
    bf16x8 aS0 = *reinterpret_cast<const bf16x8*>(arow);
    bf16x8 aS1 = *reinterpret_cast<const bf16x8*>(arow + 32);
    bf16x8 aX0 = *reinterpret_cast<const bf16x8*>(arow + 64);
    bf16x8 aX1 = *reinterpret_cast<const bf16x8*>(arow + 96);

    bf16x8 aM0, aM1;
    #pragma unroll
    for (int j = 0; j < 8; ++j) {
        aM0[j] = (short)f2bf(bf2f((ushort)aS0[j]) * inv);
        aM1[j] = (short)f2bf(bf2f((ushort)aS1[j]) * inv);
    }

    f32x4 acc = { bo, bo, bo, bo };
    acc = __builtin_amdgcn_mfma_f32_16x16x32_bf16(aS0, bS0, acc, 0, 0, 0);
    acc = __builtin_amdgcn_mfma_f32_16x16x32_bf16(aS1, bS1, acc, 0, 0, 0);
    acc = __builtin_amdgcn_mfma_f32_16x16x32_bf16(aM0, bM0, acc, 0, 0, 0);
    acc = __builtin_amdgcn_mfma_f32_16x16x32_bf16(aM1, bM1, acc, 0, 0, 0);
    acc = __builtin_amdgcn_mfma_f32_16x16x32_bf16(aX0, bX0, acc, 0, 0, 0);
    acc = __builtin_amdgcn_mfma_f32_16x16x32_bf16(aX1, bX1, acc, 0, 0, 0);

    int rbase = n0 + ((lane >> 4) << 2);
    #pragma unroll
    for (int r = 0; r < 4; ++r)
        out[(size_t)(rbase + r) * D + col] = acc[r];
}

extern "C" void kernel_launch(void* const* d_in, const int* in_sizes, int n_in,
                              void* d_out, int out_size, void* d_ws, size_t ws_size,
                              hipStream_t stream)
{
    const float* x  = (const float*)d_in[0];
    const int*   ei = (const int*)d_in[1];
    const float* W  = (const float*)d_in[2];
    const float* b  = (const float*)d_in[3];
    float* out = (float*)d_out;

    int N = in_sizes[0] / D;
    int E = in_sizes[1] / 2;
    const int* srcv = ei;
    const int* dstv = ei + E;

    int NB  = (N + NPB - 1) / NPB;          // 782 buckets
    int EPB = (E + NBLK - 1) / NBLK;
    int M   = NB * NBLK;                    // 200192

    unsigned* bcntT    = (unsigned*)d_ws;          // [M]   0.8MB
    unsigned* bbaseT   = bcntT + M;                // [M]   0.8MB
    unsigned* partials = bbaseT + M;               // [128]
    unsigned* cnt      = partials + 128;           // [N]   0.4MB
    unsigned* binned   = cnt + N;                  // [E]   5MB
    ushort*   xb       = (ushort*)(binned + E);    // [N*64]  12.8MB
    ushort*   Wb       = xb + (size_t)N * D;       // [64*192]
    ushort*   feats    = Wb + (size_t)D * F3;      // [N*128] 25.6MB  (~45.4MB total)

    int nChunksM   = (M + SCAN_CHUNK - 1) / SCAN_CHUNK;  // 98
    int n4         = N * D / 4;
    int castBlocks = (n4 + 255) / 256;

    k_cast_hist<<<NBLK + castBlocks + 1, 256, 0, stream>>>(
        x, xb, n4, W, Wb, D * F3, dstv, bcntT, E, EPB, NB, castBlocks);
    k_chunk_scan<<<nChunksM, 256, 0, stream>>>(bcntT, bbaseT, partials, M);
    k_scan_partials<<<1, 64, 0, stream>>>(partials, nChunksM);
    k_bin_scatter<<<NBLK, 256, 0, stream>>>(srcv, dstv, bbaseT, partials,
                                            binned, E, EPB, NB);
    k_bucket_agg<<<NB, 512, 0, stream>>>(binned, bbaseT, partials, xb,
                                         cnt, feats, E, NB, N);
    k_mlp2<<<N / 16, 256, 0, stream>>>(feats, cnt, Wb, b, out, N);
}

// Round 12
// 117.538 us; speedup vs baseline: 5.3153x; 5.3153x over previous
//
#include <hip/hip_runtime.h>
#include <hip/hip_bf16.h>
#include <math.h>

#define D    64
#define F3   192
#define FS   128          // stored feats channels: [sum(64) | max(64)]
#define NPB  256          // nodes per bucket (local dst = 8 bits)
#define LBITS 8
#define SBITS 17          // src id fits in 17 bits (N=100000 < 131072)
#define NBLK 256          // edge blocks for binning passes
#define SCAN_CHUNK 2048   // 256 threads * 8 elements (== 1<<11)
#define BUCKET_PAD 1800   // per-bucket ssrc slack: 256 nodes * 7 + align
#define SSRC_CAP   2000000

using bf16x8 = __attribute__((ext_vector_type(8))) short;
using f32x4  = __attribute__((ext_vector_type(4))) float;

__device__ __forceinline__ ushort f2bf(float f) {
    __hip_bfloat16 h = __float2bfloat16(f);
    return *reinterpret_cast<ushort*>(&h);
}
__device__ __forceinline__ float bf2f(ushort u) {
    unsigned v = ((unsigned)u) << 16;
    return __uint_as_float(v);
}

// ---------------- A1 + pre-cast: hist | xcast | wcast by block range -------
__global__ __launch_bounds__(256) void k_cast_hist(
    const float* __restrict__ x, ushort* __restrict__ xb, int n4,
    const float* __restrict__ W, ushort* __restrict__ Wb, int nW,
    const int* __restrict__ dstv, unsigned* __restrict__ bcntT,
    int E, int EPB, int NB, int castBlocks)
{
    int bid = blockIdx.x;
    if (bid < NBLK) {
        __shared__ unsigned h[512];
        for (int i = threadIdx.x; i < NB; i += 256) h[i] = 0;
        __syncthreads();
        int lo = bid * EPB, hi = min(E, lo + EPB);
        for (int e = lo + threadIdx.x; e < hi; e += 256)
            atomicAdd(&h[((unsigned)dstv[e]) >> LBITS], 1u);
        __syncthreads();
        for (int i = threadIdx.x; i < NB; i += 256)
            bcntT[(size_t)i * NBLK + bid] = h[i];
    } else if (bid < NBLK + castBlocks) {
        int i = (bid - NBLK) * 256 + threadIdx.x;
        if (i < n4) {
            float4 v = *reinterpret_cast<const float4*>(x + (size_t)i * 4);
            ushort4 u = { f2bf(v.x), f2bf(v.y), f2bf(v.z), f2bf(v.w) };
            *reinterpret_cast<ushort4*>(xb + (size_t)i * 4) = u;
        }
    } else {
        for (int i = threadIdx.x; i < nW; i += 256) Wb[i] = f2bf(W[i]);
    }
}

// ---------------- A2: chunked exclusive scan of the [bucket][block] matrix --
__global__ __launch_bounds__(256) void k_chunk_scan(
    const unsigned* __restrict__ cnt, unsigned* __restrict__ offs,
    unsigned* __restrict__ partials, int N)
{
    __shared__ unsigned ts[256];
    int t = threadIdx.x;
    int ebase = blockIdx.x * SCAN_CHUNK + t * 8;
    unsigned v[8];
    unsigned s = 0;
    #pragma unroll
    for (int j = 0; j < 8; ++j) {
        unsigned c = (ebase + j < N) ? cnt[ebase + j] : 0u;
        v[j] = s; s += c;
    }
    ts[t] = s;
    __syncthreads();
    #pragma unroll
    for (int off = 1; off < 256; off <<= 1) {
        unsigned add = (t >= off) ? ts[t - off] : 0u;
        __syncthreads();
        ts[t] += add;
        __syncthreads();
    }
    unsigned tb = (t > 0) ? ts[t - 1] : 0u;
    #pragma unroll
    for (int j = 0; j < 8; ++j)
        if (ebase + j < N) offs[ebase + j] = tb + v[j];
    if (t == 255) partials[blockIdx.x] = ts[255];
}

// inline exclusive scan of chunk partials (<=64 entries) into LDS
__device__ __forceinline__ void scan_partials_lds(
    const unsigned* __restrict__ partials, unsigned* psc, int n, int t)
{
    __shared__ unsigned raw[64];
    if (t < n) raw[t] = partials[t];
    __syncthreads();
    if (t == 0) {
        unsigned s = 0;
        for (int i = 0; i < n; ++i) { unsigned c = raw[i]; psc[i] = s; s += c; }
    }
    __syncthreads();
}

// ---------------- A3: scatter edges into bucket-grouped storage -------------
__global__ __launch_bounds__(256) void k_bin_scatter(
    const int* __restrict__ srcv, const int* __restrict__ dstv,
    const unsigned* __restrict__ bbaseT, const unsigned* __restrict__ partials,
    int nChunks, unsigned* __restrict__ binned, int E, int EPB, int NB)
{
    __shared__ unsigned cur[512];
    __shared__ unsigned psc[64];
    int t = threadIdx.x;
    scan_partials_lds(partials, psc, nChunks, t);
    for (int i = t; i < NB; i += 256) {
        unsigned idx = (unsigned)i * NBLK + blockIdx.x;
        cur[i] = bbaseT[idx] + psc[idx >> 11];
    }
    __syncthreads();
    int lo = blockIdx.x * EPB, hi = min(E, lo + EPB);
    for (int e = lo + t; e < hi; e += 256) {
        unsigned d = (unsigned)dstv[e];
        unsigned s = (unsigned)srcv[e];
        unsigned p = atomicAdd(&cur[d >> LBITS], 1u);
        binned[p] = ((d & (NPB - 1u)) << SBITS) | s;
    }
}

// ---------------- A4: per-bucket CSR with 8-aligned padded node segments ----
__global__ __launch_bounds__(256) void k_bucket_csr(
    const unsigned* __restrict__ binned, const unsigned* __restrict__ bbaseT,
    const unsigned* __restrict__ partials, int nChunks,
    unsigned* __restrict__ offs, unsigned* __restrict__ cnt,
    unsigned* __restrict__ ssrc, int E, int NB, int N)
{
    __shared__ unsigned c[256];
    __shared__ unsigned ts[256];
    __shared__ unsigned psc[64];
    int k = blockIdx.x;
    int t = threadIdx.x;
    scan_partials_lds(partials, psc, nChunks, t);

    unsigned i0 = (unsigned)k * NBLK;
    unsigned bstart = bbaseT[i0] + psc[i0 >> 11];
    unsigned bend;
    if (k + 1 < NB) {
        unsigned i1 = (unsigned)(k + 1) * NBLK;
        bend = bbaseT[i1] + psc[i1 >> 11];
    } else bend = (unsigned)E;
    unsigned bstartPad = ((bstart + 7u) & ~7u) + (unsigned)BUCKET_PAD * k;

    c[t] = 0;
    __syncthreads();
    for (unsigned e = bstart + t; e < bend; e += 256)
        atomicAdd(&c[binned[e] >> SBITS], 1u);
    __syncthreads();

    unsigned myc  = c[t];
    unsigned mycp = (myc + 7u) & ~7u;        // padded to 8
    ts[t] = mycp;
    __syncthreads();
    #pragma unroll
    for (int off = 1; off < 256; off <<= 1) {
        unsigned add = (t >= off) ? ts[t - off] : 0u;
        __syncthreads();
        ts[t] += add;
        __syncthreads();
    }
    unsigned exclp = t ? ts[t - 1] : 0u;
    unsigned stPad = bstartPad + exclp;

    int gn = k * NPB + t;
    if (gn < N) { offs[gn] = stPad; cnt[gn] = myc; }

    c[t] = exclp;          // local padded cursor
    __syncthreads();
    for (unsigned e = bstart + t; e < bend; e += 256) {
        unsigned u  = binned[e];
        unsigned ld = u >> SBITS;
        unsigned r  = atomicAdd(&c[ld], 1u);
        ssrc[bstartPad + r] = u & ((1u << SBITS) - 1u);
    }
    __syncthreads();
    // pad fill: duplicate last id (sum compensated in gather; max unaffected)
    if (myc && mycp > myc) {
        unsigned lastId = ssrc[stPad + myc - 1];
        for (unsigned j = myc; j < mycp; ++j) ssrc[stPad + j] = lastId;
    }
}

// ---------------- Phase B: gather, lane = channel, 16 rows in flight --------
// Wave = node, grid-stride. Main loop consumes 16 padded edges with two
// independent accumulator sets (a: s0/m0, b: s1/m1) -> 16 outstanding
// 128B row loads; 8-tail handles the remainder. Pad duplicates compensated
// via s -= p*last (max unaffected by duplicates).
__global__ __launch_bounds__(256) void k_gather4(
    const ushort*   __restrict__ xb,      // [N][64] bf16
    const unsigned* __restrict__ ssrc,
    const unsigned* __restrict__ offs,
    const unsigned* __restrict__ cnt,
    ushort*         __restrict__ feats,   // [N][128] bf16
    int N)
{
    int tid  = threadIdx.x;
    unsigned lane = tid & 63;
    int wv   = tid >> 6;

    int nq = (N + 3) >> 2;
    for (int q = blockIdx.x; q < nq; q += gridDim.x) {
        int n = q * 4 + wv;
        if (n >= N) continue;

        unsigned st  = offs[n];
        unsigned dg  = cnt[n];
        unsigned dgp = (dg + 7u) & ~7u;

        float s0 = 0.0f, s1 = 0.0f, m0 = -INFINITY, m1 = -INFINITY;
        unsigned i = 0;
        for (; i + 16 <= dgp; i += 16) {
            uint4 ia = *reinterpret_cast<const uint4*>(ssrc + st + i);
            uint4 ib = *reinterpret_cast<const uint4*>(ssrc + st + i + 4);
            uint4 ic = *reinterpret_cast<const uint4*>(ssrc + st + i + 8);
            uint4 id = *reinterpret_cast<const uint4*>(ssrc + st + i + 12);
            float a0 = bf2f(xb[(ia.x << 6) | lane]);
            float a1 = bf2f(xb[(ia.y << 6) | lane]);
            float a2 = bf2f(xb[(ia.z << 6) | lane]);
            float a3 = bf2f(xb[(ia.w << 6) | lane]);
            float a4 = bf2f(xb[(ib.x << 6) | lane]);
            float a5 = bf2f(xb[(ib.y << 6) | lane]);
            float a6 = bf2f(xb[(ib.z << 6) | lane]);
            float a7 = bf2f(xb[(ib.w << 6) | lane]);
            float b0 = bf2f(xb[(ic.x << 6) | lane]);
            float b1 = bf2f(xb[(ic.y << 6) | lane]);
            float b2 = bf2f(xb[(ic.z << 6) | lane]);
            float b3 = bf2f(xb[(ic.w << 6) | lane]);
            float b4 = bf2f(xb[(id.x << 6) | lane]);
            float b5 = bf2f(xb[(id.y << 6) | lane]);
            float b6 = bf2f(xb[(id.z << 6) | lane]);
            float b7 = bf2f(xb[(id.w << 6) | lane]);
            s0 += ((a0 + a1) + (a2 + a3)) + ((a4 + a5) + (a6 + a7));
            s1 += ((b0 + b1) + (b2 + b3)) + ((b4 + b5) + (b6 + b7));
            m0 = fmaxf(m0, fmaxf(fmaxf(fmaxf(a0, a1), fmaxf(a2, a3)),
                                 fmaxf(fmaxf(a4, a5), fmaxf(a6, a7))));
            m1 = fmaxf(m1, fmaxf(fmaxf(fmaxf(b0, b1), fmaxf(b2, b3)),
                                 fmaxf(fmaxf(b4, b5), fmaxf(b6, b7))));
        }
        if (i < dgp) {     // one remaining 8-batch
            uint4 ia = *reinterpret_cast<const uint4*>(ssrc + st + i);
            uint4 ib = *reinterpret_cast<const uint4*>(ssrc + st + i + 4);
            float a0 = bf2f(xb[(ia.x << 6) | lane]);
            float a1 = bf2f(xb[(ia.y << 6) | lane]);
            float a2 = bf2f(xb[(ia.z << 6) | lane]);
            float a3 = bf2f(xb[(ia.w << 6) | lane]);
            float a4 = bf2f(xb[(ib.x << 6) | lane]);
            float a5 = bf2f(xb[(ib.y << 6) | lane]);
            float a6 = bf2f(xb[(ib.z << 6) | lane]);
            float a7 = bf2f(xb[(ib.w << 6) | lane]);
            s0 += ((a0 + a1) + (a2 + a3)) + ((a4 + a5) + (a6 + a7));
            m0 = fmaxf(m0, fmaxf(fmaxf(fmaxf(a0, a1), fmaxf(a2, a3)),
                                 fmaxf(fmaxf(a4, a5), fmaxf(a6, a7))));
        }
        float s = s0 + s1;
        float m = fmaxf(m0, m1);

        unsigned p = dgp - dg;
        if (p && dg) {
            unsigned lastId = ssrc[st + dg - 1];
            float last = bf2f(xb[(lastId << 6) | lane]);
            s -= (float)p * last;
        }

        size_t fb = (size_t)n * FS;
        feats[fb + lane]      = f2bf(s);
        feats[fb + 64 + lane] = dg ? f2bf(m) : (ushort)0;
    }
}

// ---------------- Phase C: MFMA MLP ----------------
__global__ __launch_bounds__(256) void k_mlp2(
    const ushort*   __restrict__ feats,   // [N][128] bf16
    const unsigned* __restrict__ cnt,
    const ushort*   __restrict__ Wb,      // [64][192] bf16
    const float*    __restrict__ bias,    // [64]
    float*          __restrict__ out,     // [N][64]
    int N)
{
    int tid  = threadIdx.x;
    int lane = tid & 63;
    int wv   = tid >> 6;
    int l16  = lane & 15;
    int kb   = (lane >> 4) << 3;

    int col = (wv << 4) + l16;
    const ushort* wp = Wb + (size_t)col * F3 + kb;
    bf16x8 bS0 = *reinterpret_cast<const bf16x8*>(wp);
    bf16x8 bS1 = *reinterpret_cast<const bf16x8*>(wp + 32);
    bf16x8 bM0 = *reinterpret_cast<const bf16x8*>(wp + 64);
    bf16x8 bM1 = *reinterpret_cast<const bf16x8*>(wp + 96);
    bf16x8 bX0 = *reinterpret_cast<const bf16x8*>(wp + 128);
    bf16x8 bX1 = *reinterpret_cast<const bf16x8*>(wp + 160);
    float bo = bias[col];

    int n0 = blockIdx.x << 4;            // N divisible by 16

    unsigned dgr = cnt[n0 + l16];
    float inv = dgr ? 1.0f / (float)dgr : 0.0f;

    const ushort* arow = feats + (size_t)(n0 + l16) * FS + kb;
    bf16x8 aS0 = *reinterpret_cast<const bf16x8*>(arow);
    bf16x8 aS1 = *reinterpret_cast<const bf16x8*>(arow + 32);
    bf16x8 aX0 = *reinterpret_cast<const bf16x8*>(arow + 64);
    bf16x8 aX1 = *reinterpret_cast<const bf16x8*>(arow + 96);

    bf16x8 aM0, aM1;
    #pragma unroll
    for (int j = 0; j < 8; ++j) {
        aM0[j] = (short)f2bf(bf2f((ushort)aS0[j]) * inv);
        aM1[j] = (short)f2bf(bf2f((ushort)aS1[j]) * inv);
    }

    f32x4 acc = { bo, bo, bo, bo };
    acc = __builtin_amdgcn_mfma_f32_16x16x32_bf16(aS0, bS0, acc, 0, 0, 0);
    acc = __builtin_amdgcn_mfma_f32_16x16x32_bf16(aS1, bS1, acc, 0, 0, 0);
    acc = __builtin_amdgcn_mfma_f32_16x16x32_bf16(aM0, bM0, acc, 0, 0, 0);
    acc = __builtin_amdgcn_mfma_f32_16x16x32_bf16(aM1, bM1, acc, 0, 0, 0);
    acc = __builtin_amdgcn_mfma_f32_16x16x32_bf16(aX0, bX0, acc, 0, 0, 0);
    acc = __builtin_amdgcn_mfma_f32_16x16x32_bf16(aX1, bX1, acc, 0, 0, 0);

    int rbase = n0 + ((lane >> 4) << 2);
    #pragma unroll
    for (int r = 0; r < 4; ++r)
        out[(size_t)(rbase + r) * D + col] = acc[r];
}

extern "C" void kernel_launch(void* const* d_in, const int* in_sizes, int n_in,
                              void* d_out, int out_size, void* d_ws, size_t ws_size,
                              hipStream_t stream)
{
    const float* x  = (const float*)d_in[0];
    const int*   ei = (const int*)d_in[1];
    const float* W  = (const float*)d_in[2];
    const float* b  = (const float*)d_in[3];
    float* out = (float*)d_out;

    int N = in_sizes[0] / D;
    int E = in_sizes[1] / 2;
    const int* srcv = ei;
    const int* dstv = ei + E;

    int NB  = (N + NPB - 1) / NPB;          // 391 buckets
    int EPB = (E + NBLK - 1) / NBLK;
    int M   = NB * NBLK;                    // 100096

    unsigned* bcntT    = (unsigned*)d_ws;          // [M]       400KB
    unsigned* bbaseT   = bcntT + M;                // [M]       400KB
    unsigned* partials = bbaseT + M;               // [64]
    unsigned* offs     = partials + 64;            // [N]       400KB
    unsigned* cnt      = offs + N;                 // [N]       400KB
    unsigned* ssrc     = cnt + N;                  // [SSRC_CAP] 8MB (padded)
    ushort*   xb       = (ushort*)(ssrc + SSRC_CAP);   // [N*64]  12.8MB
    ushort*   Wb       = xb + (size_t)N * D;           // [64*192]
    ushort*   feats    = Wb + (size_t)D * F3;          // [N*128] 25.6MB
    unsigned* binned   = (unsigned*)feats;             // [E] aliases feats (dead before gather)

    int nChunksM  = (M + SCAN_CHUNK - 1) / SCAN_CHUNK;  // 49
    int n4        = N * D / 4;
    int castBlocks = (n4 + 255) / 256;

    k_cast_hist<<<NBLK + castBlocks + 1, 256, 0, stream>>>(
        x, xb, n4, W, Wb, D * F3, dstv, bcntT, E, EPB, NB, castBlocks);
    k_chunk_scan<<<nChunksM, 256, 0, stream>>>(bcntT, bbaseT, partials, M);
    k_bin_scatter<<<NBLK, 256, 0, stream>>>(srcv, dstv, bbaseT, partials,
                                            nChunksM, binned, E, EPB, NB);
    k_bucket_csr<<<NB, 256, 0, stream>>>(binned, bbaseT, partials, nChunksM,
                                         offs, cnt, ssrc, E, NB, N);
    k_gather4<<<2048, 256, 0, stream>>>(xb, ssrc, offs, cnt, feats, N);
    k_mlp2<<<N / 16, 256, 0, stream>>>(feats, cnt, Wb, b, out, N);
}

// Round 13
// 114.447 us; speedup vs baseline: 5.4588x; 1.0270x over previous
//
#include <hip/hip_runtime.h>
#include <hip/hip_bf16.h>
#include <math.h>

#define D    64
#define F3   192
#define FS   128          // stored feats channels: [sum(64) | max(64)]
#define NPB  256          // nodes per bucket (local dst = 8 bits)
#define LBITS 8
#define SBITS 17          // src id fits in 17 bits (N=100000 < 131072)
#define NBLK 256          // edge blocks for binning passes
#define SCAN_CHUNK 2048   // 256 threads * 8 elements (== 1<<11)
#define BUCKET_PAD 1800   // per-bucket ssrc slack: 256 nodes * 7 + align
#define SSRC_CAP   2000000

using bf16x8 = __attribute__((ext_vector_type(8))) short;
using f32x4  = __attribute__((ext_vector_type(4))) float;

__device__ __forceinline__ ushort f2bf(float f) {
    __hip_bfloat16 h = __float2bfloat16(f);
    return *reinterpret_cast<ushort*>(&h);
}
__device__ __forceinline__ float bf2f(ushort u) {
    unsigned v = ((unsigned)u) << 16;
    return __uint_as_float(v);
}

// ---------------- A1 + pre-cast: hist | xcast | wcast by block range -------
__global__ __launch_bounds__(256) void k_cast_hist(
    const float* __restrict__ x, ushort* __restrict__ xb, int n4,
    const float* __restrict__ W, ushort* __restrict__ Wb, int nW,
    const int* __restrict__ dstv, unsigned* __restrict__ bcntT,
    int E, int EPB, int NB, int castBlocks)
{
    int bid = blockIdx.x;
    if (bid < NBLK) {
        __shared__ unsigned h[512];
        for (int i = threadIdx.x; i < NB; i += 256) h[i] = 0;
        __syncthreads();
        int lo = bid * EPB, hi = min(E, lo + EPB);
        for (int e = lo + threadIdx.x; e < hi; e += 256)
            atomicAdd(&h[((unsigned)dstv[e]) >> LBITS], 1u);
        __syncthreads();
        for (int i = threadIdx.x; i < NB; i += 256)
            bcntT[(size_t)i * NBLK + bid] = h[i];
    } else if (bid < NBLK + castBlocks) {
        int i = (bid - NBLK) * 256 + threadIdx.x;
        if (i < n4) {
            float4 v = *reinterpret_cast<const float4*>(x + (size_t)i * 4);
            ushort4 u = { f2bf(v.x), f2bf(v.y), f2bf(v.z), f2bf(v.w) };
            *reinterpret_cast<ushort4*>(xb + (size_t)i * 4) = u;
        }
    } else {
        for (int i = threadIdx.x; i < nW; i += 256) Wb[i] = f2bf(W[i]);
    }
}

// ---------------- A2: chunked exclusive scan of the [bucket][block] matrix --
__global__ __launch_bounds__(256) void k_chunk_scan(
    const unsigned* __restrict__ cnt, unsigned* __restrict__ offs,
    unsigned* __restrict__ partials, int N)
{
    __shared__ unsigned ts[256];
    int t = threadIdx.x;
    int ebase = blockIdx.x * SCAN_CHUNK + t * 8;
    unsigned v[8];
    unsigned s = 0;
    #pragma unroll
    for (int j = 0; j < 8; ++j) {
        unsigned c = (ebase + j < N) ? cnt[ebase + j] : 0u;
        v[j] = s; s += c;
    }
    ts[t] = s;
    __syncthreads();
    #pragma unroll
    for (int off = 1; off < 256; off <<= 1) {
        unsigned add = (t >= off) ? ts[t - off] : 0u;
        __syncthreads();
        ts[t] += add;
        __syncthreads();
    }
    unsigned tb = (t > 0) ? ts[t - 1] : 0u;
    #pragma unroll
    for (int j = 0; j < 8; ++j)
        if (ebase + j < N) offs[ebase + j] = tb + v[j];
    if (t == 255) partials[blockIdx.x] = ts[255];
}

// inline exclusive scan of chunk partials (<=64 entries) into LDS
__device__ __forceinline__ void scan_partials_lds(
    const unsigned* __restrict__ partials, unsigned* psc, int n, int t)
{
    __shared__ unsigned raw[64];
    if (t < n) raw[t] = partials[t];
    __syncthreads();
    if (t == 0) {
        unsigned s = 0;
        for (int i = 0; i < n; ++i) { unsigned c = raw[i]; psc[i] = s; s += c; }
    }
    __syncthreads();
}

// ---------------- A3: scatter edges into bucket-grouped storage -------------
__global__ __launch_bounds__(256) void k_bin_scatter(
    const int* __restrict__ srcv, const int* __restrict__ dstv,
    const unsigned* __restrict__ bbaseT, const unsigned* __restrict__ partials,
    int nChunks, unsigned* __restrict__ binned, int E, int EPB, int NB)
{
    __shared__ unsigned cur[512];
    __shared__ unsigned psc[64];
    int t = threadIdx.x;
    scan_partials_lds(partials, psc, nChunks, t);
    for (int i = t; i < NB; i += 256) {
        unsigned idx = (unsigned)i * NBLK + blockIdx.x;
        cur[i] = bbaseT[idx] + psc[idx >> 11];
    }
    __syncthreads();
    int lo = blockIdx.x * EPB, hi = min(E, lo + EPB);
    for (int e = lo + t; e < hi; e += 256) {
        unsigned d = (unsigned)dstv[e];
        unsigned s = (unsigned)srcv[e];
        unsigned p = atomicAdd(&cur[d >> LBITS], 1u);
        binned[p] = ((d & (NPB - 1u)) << SBITS) | s;
    }
}

// ---------------- A4: per-bucket CSR with 8-aligned padded node segments ----
__global__ __launch_bounds__(256) void k_bucket_csr(
    const unsigned* __restrict__ binned, const unsigned* __restrict__ bbaseT,
    const unsigned* __restrict__ partials, int nChunks,
    unsigned* __restrict__ offs, unsigned* __restrict__ cnt,
    unsigned* __restrict__ ssrc, int E, int NB, int N)
{
    __shared__ unsigned c[256];
    __shared__ unsigned ts[256];
    __shared__ unsigned psc[64];
    int k = blockIdx.x;
    int t = threadIdx.x;
    scan_partials_lds(partials, psc, nChunks, t);

    unsigned i0 = (unsigned)k * NBLK;
    unsigned bstart = bbaseT[i0] + psc[i0 >> 11];
    unsigned bend;
    if (k + 1 < NB) {
        unsigned i1 = (unsigned)(k + 1) * NBLK;
        bend = bbaseT[i1] + psc[i1 >> 11];
    } else bend = (unsigned)E;
    unsigned bstartPad = ((bstart + 7u) & ~7u) + (unsigned)BUCKET_PAD * k;

    c[t] = 0;
    __syncthreads();
    for (unsigned e = bstart + t; e < bend; e += 256)
        atomicAdd(&c[binned[e] >> SBITS], 1u);
    __syncthreads();

    unsigned myc  = c[t];
    unsigned mycp = (myc + 7u) & ~7u;        // padded to 8
    ts[t] = mycp;
    __syncthreads();
    #pragma unroll
    for (int off = 1; off < 256; off <<= 1) {
        unsigned add = (t >= off) ? ts[t - off] : 0u;
        __syncthreads();
        ts[t] += add;
        __syncthreads();
    }
    unsigned exclp = t ? ts[t - 1] : 0u;
    unsigned stPad = bstartPad + exclp;

    int gn = k * NPB + t;
    if (gn < N) { offs[gn] = stPad; cnt[gn] = myc; }

    c[t] = exclp;          // local padded cursor
    __syncthreads();
    for (unsigned e = bstart + t; e < bend; e += 256) {
        unsigned u  = binned[e];
        unsigned ld = u >> SBITS;
        unsigned r  = atomicAdd(&c[ld], 1u);
        ssrc[bstartPad + r] = u & ((1u << SBITS) - 1u);
    }
    __syncthreads();
    // pad fill: duplicate last id (sum compensated in gather; max unaffected)
    if (myc && mycp > myc) {
        unsigned lastId = ssrc[stPad + myc - 1];
        for (unsigned j = myc; j < mycp; ++j) ssrc[stPad + j] = lastId;
    }
}

// ---------------- Phase B: gather, lane = CHANNEL PAIR, 2 edges/load --------
// Wave = node, grid-stride. Lanes 0-31 process the even edge of each pair,
// lanes 32-63 the odd edge; each lane loads one dword = 2 bf16 channels of
// its edge's 128B row (two 128B segments per load instruction). Unpack is
// 2 shifts; accumulate even/odd channel in 2 regs. One load covers 2 edges
// -> per-edge VALU and VMEM both ~halved vs ushort-per-lane. Cross-half
// combine: 4 x shfl_xor(32). Pads compensated via s -= p*last.
__global__ __launch_bounds__(256) void k_gather5(
    const ushort*   __restrict__ xb,      // [N][64] bf16
    const unsigned* __restrict__ ssrc,
    const unsigned* __restrict__ offs,
    const unsigned* __restrict__ cnt,
    ushort*         __restrict__ feats,   // [N][128] bf16
    int N)
{
    const unsigned* xw = reinterpret_cast<const unsigned*>(xb);  // row = 32 dwords
    unsigned* fw = reinterpret_cast<unsigned*>(feats);           // row = 64 dwords

    int tid  = threadIdx.x;
    unsigned lane = tid & 63;
    unsigned l31  = lane & 31;
    bool     hi   = lane >= 32;
    int wv   = tid >> 6;

    int nq = (N + 3) >> 2;
    for (int q = blockIdx.x; q < nq; q += gridDim.x) {
        int n = q * 4 + wv;
        if (n >= N) continue;

        unsigned st  = offs[n];
        unsigned dg  = cnt[n];
        unsigned dgp = (dg + 7u) & ~7u;

        // accumulators: [bank0/bank1] x [even ch / odd ch]
        float se0 = 0.f, so0 = 0.f, se1 = 0.f, so1 = 0.f;
        float me0 = -INFINITY, mo0 = -INFINITY, me1 = -INFINITY, mo1 = -INFINITY;

        unsigned i = 0;
        for (; i + 16 <= dgp; i += 16) {          // 16 edges = 8 pair-loads
            uint4 ia = *reinterpret_cast<const uint4*>(ssrc + st + i);
            uint4 ib = *reinterpret_cast<const uint4*>(ssrc + st + i + 4);
            uint4 ic = *reinterpret_cast<const uint4*>(ssrc + st + i + 8);
            uint4 id = *reinterpret_cast<const uint4*>(ssrc + st + i + 12);
            unsigned p0 = hi ? ia.y : ia.x;
            unsigned p1 = hi ? ia.w : ia.z;
            unsigned p2 = hi ? ib.y : ib.x;
            unsigned p3 = hi ? ib.w : ib.z;
            unsigned p4 = hi ? ic.y : ic.x;
            unsigned p5 = hi ? ic.w : ic.z;
            unsigned p6 = hi ? id.y : id.x;
            unsigned p7 = hi ? id.w : id.z;
            unsigned w0 = xw[(p0 << 5) | l31];
            unsigned w1 = xw[(p1 << 5) | l31];
            unsigned w2 = xw[(p2 << 5) | l31];
            unsigned w3 = xw[(p3 << 5) | l31];
            unsigned w4 = xw[(p4 << 5) | l31];
            unsigned w5 = xw[(p5 << 5) | l31];
            unsigned w6 = xw[(p6 << 5) | l31];
            unsigned w7 = xw[(p7 << 5) | l31];
            #pragma unroll
            for (int j = 0; j < 8; ++j) {
                unsigned w = (j==0)?w0:(j==1)?w1:(j==2)?w2:(j==3)?w3:
                             (j==4)?w4:(j==5)?w5:(j==6)?w6:w7;
                float fe = __uint_as_float(w << 16);
                float fo = __uint_as_float(w & 0xFFFF0000u);
                if (j & 1) {
                    se1 += fe; so1 += fo;
                    me1 = fmaxf(me1, fe); mo1 = fmaxf(mo1, fo);
                } else {
                    se0 += fe; so0 += fo;
                    me0 = fmaxf(me0, fe); mo0 = fmaxf(mo0, fo);
                }
            }
        }
        if (i < dgp) {                             // one 8-edge batch = 4 pairs
            uint4 ia = *reinterpret_cast<const uint4*>(ssrc + st + i);
            uint4 ib = *reinterpret_cast<const uint4*>(ssrc + st + i + 4);
            unsigned p0 = hi ? ia.y : ia.x;
            unsigned p1 = hi ? ia.w : ia.z;
            unsigned p2 = hi ? ib.y : ib.x;
            unsigned p3 = hi ? ib.w : ib.z;
            unsigned w0 = xw[(p0 << 5) | l31];
            unsigned w1 = xw[(p1 << 5) | l31];
            unsigned w2 = xw[(p2 << 5) | l31];
            unsigned w3 = xw[(p3 << 5) | l31];
            #pragma unroll
            for (int j = 0; j < 4; ++j) {
                unsigned w = (j==0)?w0:(j==1)?w1:(j==2)?w2:w3;
                float fe = __uint_as_float(w << 16);
                float fo = __uint_as_float(w & 0xFFFF0000u);
                if (j & 1) {
                    se1 += fe; so1 += fo;
                    me1 = fmaxf(me1, fe); mo1 = fmaxf(mo1, fo);
                } else {
                    se0 += fe; so0 += fo;
                    me0 = fmaxf(me0, fe); mo0 = fmaxf(mo0, fo);
                }
            }
        }

        float se = se0 + se1, so = so0 + so1;
        float me = fmaxf(me0, me1), mo = fmaxf(mo0, mo1);
        // combine halves (even-slot sums in lanes 0-31, odd-slot in 32-63)
        se += __shfl_xor(se, 32);
        so += __shfl_xor(so, 32);
        me = fmaxf(me, __shfl_xor(me, 32));
        mo = fmaxf(mo, __shfl_xor(mo, 32));

        unsigned p = dgp - dg;
        if (p && dg) {                             // pad compensation
            unsigned lastId = ssrc[st + dg - 1];
            unsigned w = xw[(lastId << 5) | l31];
            se -= (float)p * __uint_as_float(w << 16);
            so -= (float)p * __uint_as_float(w & 0xFFFF0000u);
        }
        if (!dg) { me = 0.0f; mo = 0.0f; }

        // lanes 0-31 write the sum dword, lanes 32-63 the max dword.
        float v0 = hi ? me : se;
        float v1 = hi ? mo : so;
        unsigned outw = ((unsigned)f2bf(v0)) | (((unsigned)f2bf(v1)) << 16);
        fw[((size_t)n << 6) | lane] = outw;
    }
}

// ---------------- Phase C: MFMA MLP ----------------
__global__ __launch_bounds__(256) void k_mlp2(
    const ushort*   __restrict__ feats,   // [N][128] bf16
    const unsigned* __restrict__ cnt,
    const ushort*   __restrict__ Wb,      // [64][192] bf16
    const float*    __restrict__ bias,    // [64]
    float*          __restrict__ out,     // [N][64]
    int N)
{
    int tid  = threadIdx.x;
    int lane = tid & 63;
    int wv   = tid >> 6;
    int l16  = lane & 15;
    int kb   = (lane >> 4) << 3;

    int col = (wv << 4) + l16;
    const ushort* wp = Wb + (size_t)col * F3 + kb;
    bf16x8 bS0 = *reinterpret_cast<const bf16x8*>(wp);
    bf16x8 bS1 = *reinterpret_cast<const bf16x8*>(wp + 32);
    bf16x8 bM0 = *reinterpret_cast<const bf16x8*>(wp + 64);
    bf16x8 bM1 = *reinterpret_cast<const bf16x8*>(wp + 96);
    bf16x8 bX0 = *reinterpret_cast<const bf16x8*>(wp + 128);
    bf16x8 bX1 = *reinterpret_cast<const bf16x8*>(wp + 160);
    float bo = bias[col];

    int n0 = blockIdx.x << 4;            // N divisible by 16

    unsigned dgr = cnt[n0 + l16];
    float inv = dgr ? 1.0f / (float)dgr : 0.0f;

    const ushort* arow = feats + (size_t)(n0 + l16) * FS + kb;
    bf16x8 aS0 = *reinterpret_cast<const bf16x8*>(arow);
    bf16x8 aS1 = *reinterpret_cast<const bf16x8*>(arow + 32);
    bf16x8 aX0 = *reinterpret_cast<const bf16x8*>(arow + 64);
    bf16x8 aX1 = *reinterpret_cast<const bf16x8*>(arow + 96);

    bf16x8 aM0, aM1;
    #pragma unroll
    for (int j = 0; j < 8; ++j) {
        aM0[j] = (short)f2bf(bf2f((ushort)aS0[j]) * inv);
        aM1[j] = (short)f2bf(bf2f((ushort)aS1[j]) * inv);
    }

    f32x4 acc = { bo, bo, bo, bo };
    acc = __builtin_amdgcn_mfma_f32_16x16x32_bf16(aS0, bS0, acc, 0, 0, 0);
    acc = __builtin_amdgcn_mfma_f32_16x16x32_bf16(aS1, bS1, acc, 0, 0, 0);
    acc = __builtin_amdgcn_mfma_f32_16x16x32_bf16(aM0, bM0, acc, 0, 0, 0);
    acc = __builtin_amdgcn_mfma_f32_16x16x32_bf16(aM1, bM1, acc, 0, 0, 0);
    acc = __builtin_amdgcn_mfma_f32_16x16x32_bf16(aX0, bX0, acc, 0, 0, 0);
    acc = __builtin_amdgcn_mfma_f32_16x16x32_bf16(aX1, bX1, acc, 0, 0, 0);

    int rbase = n0 + ((lane >> 4) << 2);
    #pragma unroll
    for (int r = 0; r < 4; ++r)
        out[(size_t)(rbase + r) * D + col] = acc[r];
}

extern "C" void kernel_launch(void* const* d_in, const int* in_sizes, int n_in,
                              void* d_out, int out_size, void* d_ws, size_t ws_size,
                              hipStream_t stream)
{
    const float* x  = (const float*)d_in[0];
    const int*   ei = (const int*)d_in[1];
    const float* W  = (const float*)d_in[2];
    const float* b  = (const float*)d_in[3];
    float* out = (float*)d_out;

    int N = in_sizes[0] / D;
    int E = in_sizes[1] / 2;
    const int* srcv = ei;
    const int* dstv = ei + E;

    int NB  = (N + NPB - 1) / NPB;          // 391 buckets
    int EPB = (E + NBLK - 1) / NBLK;
    int M   = NB * NBLK;                    // 100096

    unsigned* bcntT    = (unsigned*)d_ws;          // [M]       400KB
    unsigned* bbaseT   = bcntT + M;                // [M]       400KB
    unsigned* partials = bbaseT + M;               // [64]
    unsigned* offs     = partials + 64;            // [N]       400KB
    unsigned* cnt      = offs + N;                 // [N]       400KB
    unsigned* ssrc     = cnt + N;                  // [SSRC_CAP] 8MB (padded)
    ushort*   xb       = (ushort*)(ssrc + SSRC_CAP);   // [N*64]  12.8MB
    ushort*   Wb       = xb + (size_t)N * D;           // [64*192]
    ushort*   feats    = Wb + (size_t)D * F3;          // [N*128] 25.6MB
    unsigned* binned   = (unsigned*)feats;             // [E] aliases feats (dead before gather)

    int nChunksM  = (M + SCAN_CHUNK - 1) / SCAN_CHUNK;  // 49
    int n4        = N * D / 4;
    int castBlocks = (n4 + 255) / 256;

    k_cast_hist<<<NBLK + castBlocks + 1, 256, 0, stream>>>(
        x, xb, n4, W, Wb, D * F3, dstv, bcntT, E, EPB, NB, castBlocks);
    k_chunk_scan<<<nChunksM, 256, 0, stream>>>(bcntT, bbaseT, partials, M);
    k_bin_scatter<<<NBLK, 256, 0, stream>>>(srcv, dstv, bbaseT, partials,
                                            nChunksM, binned, E, EPB, NB);
    k_bucket_csr<<<NB, 256, 0, stream>>>(binned, bbaseT, partials, nChunksM,
                                         offs, cnt, ssrc, E, NB, N);
    k_gather5<<<2048, 256, 0, stream>>>(xb, ssrc, offs, cnt, feats, N);
    k_mlp2<<<N / 16, 256, 0, stream>>>(feats, cnt, Wb, b, out, N);
}